// Round 4
// baseline (132.506 us; speedup 1.0000x reference)
//
#include <hip/hip_runtime.h>
#include <hip/hip_bf16.h>
#include <cstddef>

// Problem constants (EmbeddingEngine_47029891891415)
#define S_ 4
#define N_ 65536
#define K_ 64
#define D_ 256
#define P_ 8192

typedef __bf16 bf16x8 __attribute__((ext_vector_type(8)));
typedef __bf16 bf16x4 __attribute__((ext_vector_type(4)));
typedef float  f32x4  __attribute__((ext_vector_type(4)));

// ws layout: [0, 256KB): wpack (131072 bf16 = 256 KB padded region)
//            [256KB, 256KB+4MB): pe_bf (8192*256 bf16 = 4 MB)
#define WPACK_ELEMS (S_ * 2 * 16 * 64 * 8)      // 65536
#define PE_OFF_BYTES (256 * 1024)

// Prep kernel. Blocks 0..255: pack W [S][64][256] f32 -> bf16 MFMA fragments:
//   wpack[(((s*2 + t)*16 + c)*64 + lane)*8 + i] =
//       bf16(W[s][t*32 + 8*(lane>>4) + i][c*16 + (lane&15)])
// Blocks 256..2303: convert pe [P*D] f32 -> bf16 (4 elems/thread).
__global__ __launch_bounds__(256) void prep_kernel(const float* __restrict__ W,
                                                   const float* __restrict__ pe,
                                                   __bf16* __restrict__ wpack,
                                                   __bf16* __restrict__ pe_bf) {
    const int b = blockIdx.x;
    if (b < 256) {
        int tid  = b * 256 + threadIdx.x;   // 0..65535
        int i    =  tid        & 7;
        int lane = (tid >> 3)  & 63;
        int c    = (tid >> 9)  & 15;
        int t    = (tid >> 13) & 1;
        int s    =  tid >> 14;
        int k    = t * 32 + 8 * (lane >> 4) + i;
        int col  = c * 16 + (lane & 15);
        wpack[tid] = (__bf16)W[(s * K_ + k) * D_ + col];
    } else {
        int t = (b - 256) * 256 + threadIdx.x;      // 0..524287
        f32x4 v = __builtin_nontemporal_load((const f32x4*)(pe + (size_t)t * 4));
        bf16x4 o;
        o[0] = (__bf16)v[0]; o[1] = (__bf16)v[1];
        o[2] = (__bf16)v[2]; o[3] = (__bf16)v[3];
        *(bf16x4*)(pe_bf + (size_t)t * 4) = o;      // normal store: want it cached
    }
}

// One block = one stream s, one 64-token tile. 4 waves; wave w owns tokens
// [tile*64 + w*16, +16) x all 256 D-cols.
// Swapped-operand MFMA: D[i=d_local][j=token_local] = sum_k W[k][d] * tok[j][k]
// C/D layout (m89/m91): col(lane&15) = token j, row(g*4+reg) = d_local
// -> each lane owns 4 CONSECUTIVE d elements of one token.
__global__ __launch_bounds__(256) void embed_kernel(
        const float* __restrict__ tokens,    // [S][N][K] f32
        const float* __restrict__ bvec,      // [S][D] f32
        const int*   __restrict__ idxs,      // [S][N] i32
        const int*   __restrict__ idxs_pe,   // [S][N] i32
        const __bf16* __restrict__ wpack,    // packed W fragments (L2)
        const __bf16* __restrict__ pe_bf,    // [P][D] bf16 (fits per-XCD L2)
        float* __restrict__ out) {           // [S*N][D] f32
    const int blk   = blockIdx.x;            // 0..4095
    const int s     = blk >> 10;             // 1024 tiles per stream
    const int tile  = blk & 1023;
    const int wave  = threadIdx.x >> 6;
    const int lane  = threadIdx.x & 63;
    const int j     = lane & 15;             // token within wave tile
    const int g     = lane >> 4;
    const int rowbase = tile * 64 + wave * 16;
    const int trowi   = rowbase + j;         // token row within stream

    // ---- indices + pe gathers issued FIRST (latency hides under MFMA)
    const int orow = idxs   [s * N_ + trowi];
    const int ipe  = idxs_pe[s * N_ + trowi];
    const __bf16* __restrict__ perow = pe_bf + (size_t)ipe * D_ + g * 4;
    bf16x4 pev[16];
#pragma unroll
    for (int c = 0; c < 16; ++c)
        pev[c] = *(const bf16x4*)(perow + c * 16);

    // ---- token B-fragments: tok[trowi][k], k = t*32 + 8g + e (streaming)
    const float* trow = tokens + ((size_t)s * N_ + trowi) * K_;
    f32x4 t0lo = __builtin_nontemporal_load((const f32x4*)(trow +      8 * g));
    f32x4 t0hi = __builtin_nontemporal_load((const f32x4*)(trow +      8 * g + 4));
    f32x4 t1lo = __builtin_nontemporal_load((const f32x4*)(trow + 32 + 8 * g));
    f32x4 t1hi = __builtin_nontemporal_load((const f32x4*)(trow + 32 + 8 * g + 4));
    bf16x8 a0, a1;
#pragma unroll
    for (int e = 0; e < 4; ++e) {
        a0[e]     = (__bf16)t0lo[e];
        a0[e + 4] = (__bf16)t0hi[e];
        a1[e]     = (__bf16)t1lo[e];
        a1[e + 4] = (__bf16)t1hi[e];
    }

    // ---- W fragments (L2-resident) + MFMA (swapped operands)
    const bf16x8* wp0 = (const bf16x8*)wpack + (size_t)((s * 2 + 0) * 16) * 64;
    const bf16x8* wp1 = (const bf16x8*)wpack + (size_t)((s * 2 + 1) * 16) * 64;

    f32x4 acc[16];
#pragma unroll
    for (int c = 0; c < 16; ++c) acc[c] = (f32x4){0.f, 0.f, 0.f, 0.f};
#pragma unroll
    for (int c = 0; c < 16; ++c) {
        bf16x8 w0 = wp0[c * 64 + lane];
        bf16x8 w1 = wp1[c * 64 + lane];
        acc[c] = __builtin_amdgcn_mfma_f32_16x16x32_bf16(w0, a0, acc[c], 0, 0, 0);
        acc[c] = __builtin_amdgcn_mfma_f32_16x16x32_bf16(w1, a1, acc[c], 0, 0, 0);
    }

    // ---- Epilogue: lane owns token trowi, d = c*16 + g*4 + {0..3}
    const float* __restrict__ brow = bvec + s * D_ + g * 4;
    float* __restrict__ optr       = out + (size_t)orow * D_ + g * 4;
#pragma unroll
    for (int c = 0; c < 16; ++c) {
        f32x4 bbv = *(const f32x4*)(brow + c * 16);
        f32x4 o;
#pragma unroll
        for (int e = 0; e < 4; ++e)
            o[e] = acc[c][e] + bbv[e] + (float)pev[c][e];
        __builtin_nontemporal_store(o, (f32x4*)(optr + c * 16));
    }
}

extern "C" void kernel_launch(void* const* d_in, const int* in_sizes, int n_in,
                              void* d_out, int out_size, void* d_ws, size_t ws_size,
                              hipStream_t stream) {
    const float* tokens  = (const float*)d_in[0];
    const float* W       = (const float*)d_in[1];
    const float* bvec    = (const float*)d_in[2];
    const float* pe      = (const float*)d_in[3];
    const int*   idxs    = (const int*)d_in[4];
    const int*   idxs_pe = (const int*)d_in[5];
    float* out = (float*)d_out;
    __bf16* wpack = (__bf16*)d_ws;
    __bf16* pe_bf = (__bf16*)((char*)d_ws + PE_OFF_BYTES);

    prep_kernel<<<256 + (P_ * D_ / 4 / 256), 256, 0, stream>>>(W, pe, wpack, pe_bf);
    embed_kernel<<<S_ * (N_ / 64), 256, 0, stream>>>(tokens, bvec, idxs, idxs_pe,
                                                     wpack, pe_bf, out);
}